// Round 7
// baseline (683.360 us; speedup 1.0000x reference)
//
#include <hip/hip_runtime.h>
#include <hip/hip_bf16.h>
#include <stdint.h>

#define Bz 8
#define Tz 2048
#define Cz 768
#define Hz 12
#define Dz 64
#define Mz (Bz*Tz)          // 16384
#define N3 (3*Cz)           // 2304
#define YSZ ((size_t)Mz*Cz) // 12582912

#define SCL 0.18033688011112042f  // log2(e) / sqrt(64)
#define KVB 64
#define QBLK 128

typedef __bf16 bf16;
typedef __attribute__((ext_vector_type(8))) bf16 bf16x8;
typedef __attribute__((ext_vector_type(4))) bf16 bf16x4;
typedef __attribute__((ext_vector_type(4))) float f32x4;

#define MFMA(A_,B_,C_) __builtin_amdgcn_mfma_f32_16x16x32_bf16(A_,B_,C_,0,0,0)

__device__ __forceinline__ void gll16(const void* g, void* l) {
  __builtin_amdgcn_global_load_lds(
      (const __attribute__((address_space(1))) void*)g,
      (__attribute__((address_space(3))) void*)l, 16, 0, 0);
}

// ---------------- prep: x fp32 -> bf16 ----------------
__global__ __launch_bounds__(256) void prep_x(const float* __restrict__ x,
                                              bf16* __restrict__ xb) {
  int i = blockIdx.x*blockDim.x + threadIdx.x;
  int stride = gridDim.x*blockDim.x;
  const float4* x4 = (const float4*)x;
  int n4 = (int)(YSZ/4);
  for (int j = i; j < n4; j += stride) {
    float4 f = x4[j];
    bf16x4 o = { (bf16)f.x, (bf16)f.y, (bf16)f.z, (bf16)f.w };
    *(bf16x4*)(xb + 4*(size_t)j) = o;
  }
}

// ---------------- prep: transpose+convert W [R][Ncol] f32 -> Wt [Ncol][R] bf16 ----------------
__global__ __launch_bounds__(256) void transpose_conv(const float* __restrict__ src,
                                                      bf16* __restrict__ dst,
                                                      int R, int Ncol) {
  __shared__ float tile[32][33];
  int bx = blockIdx.x, by = blockIdx.y;
  int tx = threadIdx.x & 31, ty = threadIdx.x >> 5;
  #pragma unroll
  for (int i = 0; i < 4; ++i)
    tile[ty + 8*i][tx] = src[(size_t)(by*32 + ty + 8*i)*Ncol + bx*32 + tx];
  __syncthreads();
  #pragma unroll
  for (int i = 0; i < 4; ++i)
    dst[(size_t)(bx*32 + ty + 8*i)*R + by*32 + tx] = (bf16)tile[tx][ty + 8*i];
}

// ---------------- GEMM: C[M,N] = A[M,K] * Bt[N,K]^T  (m97 structure) ----------------
// EPI 0: qkv epilogue. q -> qws bf16 (pre-scaled); k -> kout f32 + kws bf16;
//        v -> vout f32 + vtb bf16 transposed [BH][D][T] with kv-permuted T axis.
// EPI 1: y = acc + bias (f32)
template<int EPI>
__global__ __launch_bounds__(256) void gemm128(
    const bf16* __restrict__ A, const bf16* __restrict__ Bt,
    int Kdim, int Mtiles, int Ntiles,
    const float* __restrict__ bias,
    bf16* __restrict__ qws, bf16* __restrict__ kws, bf16* __restrict__ vtb,
    float* __restrict__ kout, float* __restrict__ vout,
    float* __restrict__ yout)
{
  __shared__ alignas(16) bf16 sA[128*32];
  __shared__ alignas(16) bf16 sB[128*32];
  int nwg = Mtiles*Ntiles;
  int bid = blockIdx.x;
  int cpx = nwg >> 3;
  int swz = (bid & 7)*cpx + (bid >> 3);
  int mtile = swz % Mtiles, ntile = swz / Mtiles;
  int tid = threadIdx.x, w = tid >> 6, l = tid & 63;
  int wr = w >> 1, wc = w & 1;
  const int rowBase = mtile*128, colBase = ntile*128;

  f32x4 acc[4][4] = {};

  int srow = w*32 + (l >> 2);
  int skoff = (l & 3)*8;
  const bf16* gA = A + (size_t)(rowBase + srow)*Kdim + skoff;
  const bf16* gB = Bt + (size_t)(colBase + srow)*Kdim + skoff;
  bf16* lA = sA + w*1024;
  bf16* lB = sB + w*1024;

  int lr = l & 15, lk = (l >> 4)*8;

  for (int k0 = 0; k0 < Kdim; k0 += 32) {
    gll16(gA,                   lA);
    gll16(gA + (size_t)16*Kdim, lA + 512);
    gll16(gB,                   lB);
    gll16(gB + (size_t)16*Kdim, lB + 512);
    gA += 32; gB += 32;
    __syncthreads();
    bf16x8 af[4], bfr[4];
    #pragma unroll
    for (int m = 0; m < 4; ++m)
      af[m] = *(const bf16x8*)(sA + (size_t)(wr*64 + m*16 + lr)*32 + lk);
    #pragma unroll
    for (int n = 0; n < 4; ++n)
      bfr[n] = *(const bf16x8*)(sB + (size_t)(wc*64 + n*16 + lr)*32 + lk);
    #pragma unroll
    for (int m = 0; m < 4; ++m)
      #pragma unroll
      for (int n = 0; n < 4; ++n)
        acc[m][n] = MFMA(af[m], bfr[n], acc[m][n]);
    __syncthreads();
  }

  #pragma unroll
  for (int m = 0; m < 4; ++m) {
    #pragma unroll
    for (int n = 0; n < 4; ++n) {
      int gcol = colBase + wc*64 + n*16 + lr;
      float bv = bias[gcol];
      int grow0 = rowBase + wr*64 + m*16 + (l >> 4)*4;
      if (EPI == 1) {
        #pragma unroll
        for (int r = 0; r < 4; ++r)
          yout[(size_t)(grow0 + r)*Cz + gcol] = acc[m][n][r] + bv;
      } else {
        int which = gcol / Cz;               // uniform over r (16-col blocks)
        int within = gcol - which*Cz;
        int h = within >> 6, d = within & 63;
        int bidx = grow0 >> 11;              // same for r=0..3 (tile 128-aligned)
        int t0 = grow0 & 2047;
        size_t bhTD = ((size_t)bidx*Hz + h);
        if (which == 0) {
          bf16* qp = qws + (bhTD*Tz + t0)*Dz + d;
          #pragma unroll
          for (int r = 0; r < 4; ++r)
            qp[(size_t)r*Dz] = (bf16)((acc[m][n][r] + bv) * SCL);
        } else if (which == 1) {
          float* kp = kout + (bhTD*Tz + t0)*Dz + d;
          bf16*  kp2 = kws + (bhTD*Tz + t0)*Dz + d;
          #pragma unroll
          for (int r = 0; r < 4; ++r) {
            float v = acc[m][n][r] + bv;
            kp[(size_t)r*Dz] = v;
            kp2[(size_t)r*Dz] = (bf16)v;
          }
        } else {
          float* vp = vout + (bhTD*Tz + t0)*Dz + d;
          bf16x4 pk;
          #pragma unroll
          for (int r = 0; r < 4; ++r) {
            float v = acc[m][n][r] + bv;
            vp[(size_t)r*Dz] = v;
            pk[r] = (bf16)v;
          }
          // transposed + kv-permuted store: slot s in each 32-block holds
          // true kv = 16*((s>>2)&1) + 4*(s>>3) + (s&3); inverse applied here.
          int ts = (t0 & ~31) | (((t0 >> 2) & 3) << 3) | (((t0 >> 4) & 1) << 2) | (t0 & 3);
          *(bf16x4*)(vtb + (bhTD*Dz + d)*Tz + ts) = pk;
        }
      }
    }
  }
}

// ---------------- flash attention (causal), QBLK=128, 8 waves, KVB=64 ----------------
__device__ __forceinline__ void stageKV(const bf16* kgb, const bf16* vgb, int kv0,
                                        char* cK, char* cV, int tid, int w) {
  int off = tid*16;                 // 0..8191 over 512 threads
  int row = off >> 7, ch = (off >> 4) & 7;
  int sw = ((ch ^ (row & 7)) << 3);
  gll16(kgb + (size_t)(kv0 + row)*Dz + sw, cK + w*1024);
  gll16(vgb + (size_t)row*Tz + kv0 + sw,   cV + w*1024);
}

__device__ __forceinline__ void attn_tile(
    int kv0, int qminw, int qmaxw, int q_l, int lr, int lg,
    const char* cK, const char* cV,
    const bf16x8& qf0, const bf16x8& qf1,
    f32x4 (&o)[4], float& mrun, float& lrun)
{
  const f32x4 zf = {0.f, 0.f, 0.f, 0.f};
  f32x4 s[4];
  // S^T[kv][q] = K * Q^T (swapped): lane owns q=q_l, kv = kv0 + n*16 + 4*lg + r
  __builtin_amdgcn_s_setprio(1);
  #pragma unroll
  for (int n = 0; n < 4; ++n) {
    int kvb = kv0 + n*16;
    if (kvb <= qmaxw) {
      int row = n*16 + lr;
      int c0 = lg ^ (lr & 7);
      bf16x8 kf0 = *(const bf16x8*)(cK + row*128 + (c0 << 4));
      bf16x8 kf1 = *(const bf16x8*)(cK + row*128 + ((c0 ^ 4) << 4));
      f32x4 t = MFMA(kf0, qf0, zf);
      s[n] = MFMA(kf1, qf1, t);
    } else {
      s[n][0] = -1e30f; s[n][1] = -1e30f; s[n][2] = -1e30f; s[n][3] = -1e30f;
    }
  }
  __builtin_amdgcn_s_setprio(0);
  // causal mask (diag blocks only; scale pre-folded into Q)
  #pragma unroll
  for (int n = 0; n < 4; ++n) {
    int kvb = kv0 + n*16;
    if (kvb <= qmaxw && kvb + 15 > qminw) {
      #pragma unroll
      for (int r = 0; r < 4; ++r)
        s[n][r] = (kvb + 4*lg + r <= q_l) ? s[n][r] : -1e30f;
    }
  }
  // in-lane max tree + 2 shfl
  f32x4 a0;
  #pragma unroll
  for (int r = 0; r < 4; ++r)
    a0[r] = fmaxf(fmaxf(s[0][r], s[1][r]), fmaxf(s[2][r], s[3][r]));
  float mx = fmaxf(fmaxf(a0[0], a0[1]), fmaxf(a0[2], a0[3]));
  mx = fmaxf(mx, __shfl_xor(mx, 16));
  mx = fmaxf(mx, __shfl_xor(mx, 32));

  bool skip = __all(mx <= mrun + 8.0f);
  float corr = 1.0f;
  if (!skip) {
    float mnew = fmaxf(mrun, mx);
    corr = exp2f(mrun - mnew);
    mrun = mnew;
  }
  f32x4 acc4 = zf;
  #pragma unroll
  for (int n = 0; n < 4; ++n) {
    #pragma unroll
    for (int r = 0; r < 4; ++r) {
      float e = exp2f(s[n][r] - mrun);
      s[n][r] = e;
      acc4[r] += e;
    }
  }
  float rs = (acc4[0] + acc4[1]) + (acc4[2] + acc4[3]);
  rs += __shfl_xor(rs, 16);
  rs += __shfl_xor(rs, 32);
  if (!skip) {
    lrun = lrun*corr + rs;
    float c0_ = __shfl(corr, 4*lg + 0);
    float c1_ = __shfl(corr, 4*lg + 1);
    float c2_ = __shfl(corr, 4*lg + 2);
    float c3_ = __shfl(corr, 4*lg + 3);
    #pragma unroll
    for (int nd = 0; nd < 4; ++nd) {
      o[nd][0] *= c0_; o[nd][1] *= c1_; o[nd][2] *= c2_; o[nd][3] *= c3_;
    }
  } else {
    lrun += rs;
  }
  // O += P V : pf built fully in-lane (V kv-axis pre-permuted to match
  // ownership: slot 8*lg+e of 32-block kk holds kv = 16*(e>>2)+4*lg+(e&3))
  __builtin_amdgcn_s_setprio(1);
  #pragma unroll
  for (int kk = 0; kk < 2; ++kk) {
    if (kv0 + kk*32 <= qmaxw) {
      bf16x8 pf;
      pf[0] = (bf16)s[2*kk][0];   pf[1] = (bf16)s[2*kk][1];
      pf[2] = (bf16)s[2*kk][2];   pf[3] = (bf16)s[2*kk][3];
      pf[4] = (bf16)s[2*kk+1][0]; pf[5] = (bf16)s[2*kk+1][1];
      pf[6] = (bf16)s[2*kk+1][2]; pf[7] = (bf16)s[2*kk+1][3];
      int cb = (kk*4 + lg) ^ (lr & 7);
      #pragma unroll
      for (int nd = 0; nd < 4; ++nd) {
        bf16x8 vf = *(const bf16x8*)(cV + (nd*16 + lr)*128 + (cb << 4));
        o[nd] = MFMA(pf, vf, o[nd]);
      }
    }
  }
  __builtin_amdgcn_s_setprio(0);
}

__global__ __launch_bounds__(512, 8) void attn128(
    const bf16* __restrict__ qws, const bf16* __restrict__ kb,
    const bf16* __restrict__ vtb, bf16* __restrict__ yatt)
{
  __shared__ alignas(16) char sK[2][8192];   // [kv][d] 128B rows, chunk ^= row&7
  __shared__ alignas(16) char sV[2][8192];   // [d][t'] 128B rows, chunk ^= row&7
  int qb = gridDim.x - 1 - blockIdx.x;       // heavy tiles first
  int bh = blockIdx.y;
  int b = bh / Hz, h = bh - b*Hz;
  int tid = threadIdx.x, w = tid >> 6, l = tid & 63;
  int lr = l & 15, lg = l >> 4;
  const int q0 = qb*QBLK;
  const int qminw = q0 + w*16;
  const int qmaxw = qminw + 15;
  const int q_l = qminw + lr;

  const bf16* qbase = qws + ((size_t)bh*Tz + qminw + lr)*Dz + lg*8;
  bf16x8 qf0 = *(const bf16x8*)qbase;
  bf16x8 qf1 = *(const bf16x8*)(qbase + 32);

  f32x4 o[4] = {};
  float mrun = -1e30f, lrun = 0.f;

  const bf16* kgb = kb  + (size_t)bh*Tz*Dz;
  const bf16* vgb = vtb + (size_t)bh*Dz*Tz;

  int nT = 2*qb + 2;
  stageKV(kgb, vgb, 0, sK[0], sV[0], tid, w);
  int buf = 0;
  for (int kt = 0; kt + 1 < nT; ++kt) {
    stageKV(kgb, vgb, (kt + 1)*KVB, sK[buf ^ 1], sV[buf ^ 1], tid, w);
    asm volatile("s_waitcnt vmcnt(2)" ::: "memory");
    __builtin_amdgcn_s_barrier();
    __builtin_amdgcn_sched_barrier(0);
    attn_tile(kt*KVB, qminw, qmaxw, q_l, lr, lg, sK[buf], sV[buf],
              qf0, qf1, o, mrun, lrun);
    asm volatile("s_waitcnt lgkmcnt(0)" ::: "memory");
    __builtin_amdgcn_s_barrier();
    __builtin_amdgcn_sched_barrier(0);
    buf ^= 1;
  }
  asm volatile("s_waitcnt vmcnt(0)" ::: "memory");
  __builtin_amdgcn_s_barrier();
  __builtin_amdgcn_sched_barrier(0);
  attn_tile((nT - 1)*KVB, qminw, qmaxw, q_l, lr, lg, sK[buf], sV[buf],
            qf0, qf1, o, mrun, lrun);

  float inv = 1.0f / lrun;
  float i0 = __shfl(inv, 4*lg + 0);
  float i1 = __shfl(inv, 4*lg + 1);
  float i2 = __shfl(inv, 4*lg + 2);
  float i3 = __shfl(inv, 4*lg + 3);
  #pragma unroll
  for (int nd = 0; nd < 4; ++nd) {
    int d = nd*16 + lr;
    int t0 = q0 + w*16 + lg*4;
    bf16* yp = yatt + ((size_t)(b*Tz + t0))*Cz + h*Dz + d;
    yp[0*Cz]   = (bf16)(o[nd][0] * i0);
    yp[1*Cz]   = (bf16)(o[nd][1] * i1);
    yp[2*Cz]   = (bf16)(o[nd][2] * i2);
    yp[3*Cz]   = (bf16)(o[nd][3] * i3);
  }
}

// ---------------- launch ----------------
extern "C" void kernel_launch(void* const* d_in, const int* in_sizes, int n_in,
                              void* d_out, int out_size, void* d_ws, size_t ws_size,
                              hipStream_t stream) {
  const float* x      = (const float*)d_in[0];
  const float* w_attn = (const float*)d_in[1];
  const float* b_attn = (const float*)d_in[2];
  const float* w_proj = (const float*)d_in[3];
  const float* b_proj = (const float*)d_in[4];

  float* y    = (float*)d_out;
  float* kout = y + YSZ;
  float* vout = y + 2*YSZ;

  char* ws = (char*)d_ws;
  bf16* xb   = (bf16*)ws;                     // 25165824 B (reused as yatt)
  bf16* qws  = (bf16*)(ws + 25165824);        // 25165824 B
  bf16* kb   = (bf16*)(ws + 50331648);        // 25165824 B
  bf16* vtb  = (bf16*)(ws + 75497472);        // 25165824 B
  bf16* wtA  = (bf16*)(ws + 100663296);       // 3538944 B
  bf16* wtP  = (bf16*)(ws + 104202240);       // 1179648 B
  bf16* yatt = xb;

  prep_x<<<2048, 256, 0, stream>>>(x, xb);
  transpose_conv<<<dim3(N3/32, Cz/32), 256, 0, stream>>>(w_attn, wtA, Cz, N3);
  transpose_conv<<<dim3(Cz/32, Cz/32), 256, 0, stream>>>(w_proj, wtP, Cz, Cz);

  gemm128<0><<<dim3((Mz/128)*(N3/128)), 256, 0, stream>>>(
      xb, wtA, Cz, Mz/128, N3/128, b_attn, qws, kb, vtb, kout, vout, nullptr);

  attn128<<<dim3(Tz/QBLK, Bz*Hz), 512, 0, stream>>>(qws, kb, vtb, yatt);

  gemm128<1><<<dim3((Mz/128)*(Cz/128)), 256, 0, stream>>>(
      yatt, wtP, Cz, Mz/128, Cz/128, b_proj, nullptr, nullptr, nullptr,
      nullptr, nullptr, y);
}

// Round 8
// 394.772 us; speedup vs baseline: 1.7310x; 1.7310x over previous
//
#include <hip/hip_runtime.h>
#include <hip/hip_bf16.h>
#include <stdint.h>

#define Bz 8
#define Tz 2048
#define Cz 768
#define Hz 12
#define Dz 64
#define Mz (Bz*Tz)          // 16384
#define N3 (3*Cz)           // 2304
#define YSZ ((size_t)Mz*Cz) // 12582912

#define SCL 0.18033688011112042f  // log2(e) / sqrt(64)
#define KVB 64
#define QBLK 128

typedef __bf16 bf16;
typedef __attribute__((ext_vector_type(8))) bf16 bf16x8;
typedef __attribute__((ext_vector_type(4))) bf16 bf16x4;
typedef __attribute__((ext_vector_type(4))) float f32x4;

#define MFMA(A_,B_,C_) __builtin_amdgcn_mfma_f32_16x16x32_bf16(A_,B_,C_,0,0,0)

__device__ __forceinline__ void gll16(const void* g, void* l) {
  __builtin_amdgcn_global_load_lds(
      (const __attribute__((address_space(1))) void*)g,
      (__attribute__((address_space(3))) void*)l, 16, 0, 0);
}

// ---------------- prep: x fp32 -> bf16 ----------------
__global__ __launch_bounds__(256) void prep_x(const float* __restrict__ x,
                                              bf16* __restrict__ xb) {
  int i = blockIdx.x*blockDim.x + threadIdx.x;
  int stride = gridDim.x*blockDim.x;
  const float4* x4 = (const float4*)x;
  int n4 = (int)(YSZ/4);
  for (int j = i; j < n4; j += stride) {
    float4 f = x4[j];
    bf16x4 o = { (bf16)f.x, (bf16)f.y, (bf16)f.z, (bf16)f.w };
    *(bf16x4*)(xb + 4*(size_t)j) = o;
  }
}

// ---------------- prep: transpose+convert W [R][Ncol] f32 -> Wt [Ncol][R] bf16 ----------------
__global__ __launch_bounds__(256) void transpose_conv(const float* __restrict__ src,
                                                      bf16* __restrict__ dst,
                                                      int R, int Ncol) {
  __shared__ float tile[32][33];
  int bx = blockIdx.x, by = blockIdx.y;
  int tx = threadIdx.x & 31, ty = threadIdx.x >> 5;
  #pragma unroll
  for (int i = 0; i < 4; ++i)
    tile[ty + 8*i][tx] = src[(size_t)(by*32 + ty + 8*i)*Ncol + bx*32 + tx];
  __syncthreads();
  #pragma unroll
  for (int i = 0; i < 4; ++i)
    dst[(size_t)(bx*32 + ty + 8*i)*R + by*32 + tx] = (bf16)tile[tx][ty + 8*i];
}

// ---------------- GEMM: C[M,N] = A[M,K] * Bt[N,K]^T  (m97 structure) ----------------
// EPI 0: qkv epilogue. q -> qws bf16 (pre-scaled); k -> kout f32 + kws bf16;
//        v -> vout f32 + vtb bf16 transposed [BH][D][T] with kv-permuted T axis.
// EPI 1: y = acc + bias (f32)
template<int EPI>
__global__ __launch_bounds__(256) void gemm128(
    const bf16* __restrict__ A, const bf16* __restrict__ Bt,
    int Kdim, int Mtiles, int Ntiles,
    const float* __restrict__ bias,
    bf16* __restrict__ qws, bf16* __restrict__ kws, bf16* __restrict__ vtb,
    float* __restrict__ kout, float* __restrict__ vout,
    float* __restrict__ yout)
{
  __shared__ alignas(16) bf16 sA[128*32];
  __shared__ alignas(16) bf16 sB[128*32];
  int nwg = Mtiles*Ntiles;
  int bid = blockIdx.x;
  int cpx = nwg >> 3;
  int swz = (bid & 7)*cpx + (bid >> 3);
  int mtile = swz % Mtiles, ntile = swz / Mtiles;
  int tid = threadIdx.x, w = tid >> 6, l = tid & 63;
  int wr = w >> 1, wc = w & 1;
  const int rowBase = mtile*128, colBase = ntile*128;

  f32x4 acc[4][4] = {};

  int srow = w*32 + (l >> 2);
  int skoff = (l & 3)*8;
  const bf16* gA = A + (size_t)(rowBase + srow)*Kdim + skoff;
  const bf16* gB = Bt + (size_t)(colBase + srow)*Kdim + skoff;
  bf16* lA = sA + w*1024;
  bf16* lB = sB + w*1024;

  int lr = l & 15, lk = (l >> 4)*8;

  for (int k0 = 0; k0 < Kdim; k0 += 32) {
    gll16(gA,                   lA);
    gll16(gA + (size_t)16*Kdim, lA + 512);
    gll16(gB,                   lB);
    gll16(gB + (size_t)16*Kdim, lB + 512);
    gA += 32; gB += 32;
    __syncthreads();
    bf16x8 af[4], bfr[4];
    #pragma unroll
    for (int m = 0; m < 4; ++m)
      af[m] = *(const bf16x8*)(sA + (size_t)(wr*64 + m*16 + lr)*32 + lk);
    #pragma unroll
    for (int n = 0; n < 4; ++n)
      bfr[n] = *(const bf16x8*)(sB + (size_t)(wc*64 + n*16 + lr)*32 + lk);
    #pragma unroll
    for (int m = 0; m < 4; ++m)
      #pragma unroll
      for (int n = 0; n < 4; ++n)
        acc[m][n] = MFMA(af[m], bfr[n], acc[m][n]);
    __syncthreads();
  }

  #pragma unroll
  for (int m = 0; m < 4; ++m) {
    #pragma unroll
    for (int n = 0; n < 4; ++n) {
      int gcol = colBase + wc*64 + n*16 + lr;
      float bv = bias[gcol];
      int grow0 = rowBase + wr*64 + m*16 + (l >> 4)*4;
      if (EPI == 1) {
        #pragma unroll
        for (int r = 0; r < 4; ++r)
          yout[(size_t)(grow0 + r)*Cz + gcol] = acc[m][n][r] + bv;
      } else {
        int which = gcol / Cz;               // uniform over r (16-col blocks)
        int within = gcol - which*Cz;
        int h = within >> 6, d = within & 63;
        int bidx = grow0 >> 11;              // same for r=0..3 (tile 128-aligned)
        int t0 = grow0 & 2047;
        size_t bhTD = ((size_t)bidx*Hz + h);
        if (which == 0) {
          bf16* qp = qws + (bhTD*Tz + t0)*Dz + d;
          #pragma unroll
          for (int r = 0; r < 4; ++r)
            qp[(size_t)r*Dz] = (bf16)((acc[m][n][r] + bv) * SCL);
        } else if (which == 1) {
          float* kp = kout + (bhTD*Tz + t0)*Dz + d;
          bf16*  kp2 = kws + (bhTD*Tz + t0)*Dz + d;
          #pragma unroll
          for (int r = 0; r < 4; ++r) {
            float v = acc[m][n][r] + bv;
            kp[(size_t)r*Dz] = v;
            kp2[(size_t)r*Dz] = (bf16)v;
          }
        } else {
          float* vp = vout + (bhTD*Tz + t0)*Dz + d;
          bf16x4 pk;
          #pragma unroll
          for (int r = 0; r < 4; ++r) {
            float v = acc[m][n][r] + bv;
            vp[(size_t)r*Dz] = v;
            pk[r] = (bf16)v;
          }
          // transposed + kv-permuted store: slot s in each 32-block holds
          // true kv = 16*((s>>2)&1) + 4*(s>>3) + (s&3); inverse applied here.
          int ts = (t0 & ~31) | (((t0 >> 2) & 3) << 3) | (((t0 >> 4) & 1) << 2) | (t0 & 3);
          *(bf16x4*)(vtb + (bhTD*Dz + d)*Tz + ts) = pk;
        }
      }
    }
  }
}

// ---------------- flash attention (causal), QBLK=128, 8 waves, KVB=64 ----------------
__device__ __forceinline__ void stageKV(const bf16* kgb, const bf16* vgb, int kv0,
                                        char* cK, char* cV, int tid, int w) {
  int off = tid*16;                 // 0..8191 over 512 threads
  int row = off >> 7, ch = (off >> 4) & 7;
  int sw = ((ch ^ (row & 7)) << 3);
  gll16(kgb + (size_t)(kv0 + row)*Dz + sw, cK + w*1024);
  gll16(vgb + (size_t)row*Tz + kv0 + sw,   cV + w*1024);
}

__device__ __forceinline__ void attn_tile(
    int kv0, int qminw, int qmaxw, int q_l, int lr, int lg,
    const char* cK, const char* cV,
    const bf16x8& qf0, const bf16x8& qf1,
    f32x4 (&o)[4], float& mrun, float& lrun)
{
  const f32x4 zf = {0.f, 0.f, 0.f, 0.f};
  f32x4 s[4];
  // S^T[kv][q] = K * Q^T (swapped): lane owns q=q_l, kv = kv0 + n*16 + 4*lg + r
  __builtin_amdgcn_s_setprio(1);
  #pragma unroll
  for (int n = 0; n < 4; ++n) {
    int kvb = kv0 + n*16;
    if (kvb <= qmaxw) {
      int row = n*16 + lr;
      int c0 = lg ^ (lr & 7);
      bf16x8 kf0 = *(const bf16x8*)(cK + row*128 + (c0 << 4));
      bf16x8 kf1 = *(const bf16x8*)(cK + row*128 + ((c0 ^ 4) << 4));
      f32x4 t = MFMA(kf0, qf0, zf);
      s[n] = MFMA(kf1, qf1, t);
    } else {
      s[n][0] = -1e30f; s[n][1] = -1e30f; s[n][2] = -1e30f; s[n][3] = -1e30f;
    }
  }
  __builtin_amdgcn_s_setprio(0);
  // causal mask (diag blocks only; scale pre-folded into Q)
  #pragma unroll
  for (int n = 0; n < 4; ++n) {
    int kvb = kv0 + n*16;
    if (kvb <= qmaxw && kvb + 15 > qminw) {
      #pragma unroll
      for (int r = 0; r < 4; ++r)
        s[n][r] = (kvb + 4*lg + r <= q_l) ? s[n][r] : -1e30f;
    }
  }
  // in-lane max tree + 2 shfl
  f32x4 a0;
  #pragma unroll
  for (int r = 0; r < 4; ++r)
    a0[r] = fmaxf(fmaxf(s[0][r], s[1][r]), fmaxf(s[2][r], s[3][r]));
  float mx = fmaxf(fmaxf(a0[0], a0[1]), fmaxf(a0[2], a0[3]));
  mx = fmaxf(mx, __shfl_xor(mx, 16));
  mx = fmaxf(mx, __shfl_xor(mx, 32));

  bool skip = __all(mx <= mrun + 8.0f);
  float corr = 1.0f;
  if (!skip) {
    float mnew = fmaxf(mrun, mx);
    corr = exp2f(mrun - mnew);
    mrun = mnew;
  }
  f32x4 acc4 = zf;
  #pragma unroll
  for (int n = 0; n < 4; ++n) {
    #pragma unroll
    for (int r = 0; r < 4; ++r) {
      float e = exp2f(s[n][r] - mrun);
      s[n][r] = e;
      acc4[r] += e;
    }
  }
  float rs = (acc4[0] + acc4[1]) + (acc4[2] + acc4[3]);
  rs += __shfl_xor(rs, 16);
  rs += __shfl_xor(rs, 32);
  if (!skip) {
    lrun = lrun*corr + rs;
    float c0_ = __shfl(corr, 4*lg + 0);
    float c1_ = __shfl(corr, 4*lg + 1);
    float c2_ = __shfl(corr, 4*lg + 2);
    float c3_ = __shfl(corr, 4*lg + 3);
    #pragma unroll
    for (int nd = 0; nd < 4; ++nd) {
      o[nd][0] *= c0_; o[nd][1] *= c1_; o[nd][2] *= c2_; o[nd][3] *= c3_;
    }
  } else {
    lrun += rs;
  }
  // O += P V : pf built fully in-lane (V kv-axis pre-permuted to match
  // ownership: slot 8*lg+e of 32-block kk holds kv = 16*(e>>2)+4*lg+(e&3))
  __builtin_amdgcn_s_setprio(1);
  #pragma unroll
  for (int kk = 0; kk < 2; ++kk) {
    if (kv0 + kk*32 <= qmaxw) {
      bf16x8 pf;
      pf[0] = (bf16)s[2*kk][0];   pf[1] = (bf16)s[2*kk][1];
      pf[2] = (bf16)s[2*kk][2];   pf[3] = (bf16)s[2*kk][3];
      pf[4] = (bf16)s[2*kk+1][0]; pf[5] = (bf16)s[2*kk+1][1];
      pf[6] = (bf16)s[2*kk+1][2]; pf[7] = (bf16)s[2*kk+1][3];
      int cb = (kk*4 + lg) ^ (lr & 7);
      #pragma unroll
      for (int nd = 0; nd < 4; ++nd) {
        bf16x8 vf = *(const bf16x8*)(cV + (nd*16 + lr)*128 + (cb << 4));
        o[nd] = MFMA(pf, vf, o[nd]);
      }
    }
  }
  __builtin_amdgcn_s_setprio(0);
}

__global__ __launch_bounds__(512, 6) void attn128(
    const bf16* __restrict__ qws, const bf16* __restrict__ kb,
    const bf16* __restrict__ vtb, bf16* __restrict__ yatt)
{
  __shared__ alignas(16) char sK[2][8192];   // [kv][d] 128B rows, chunk ^= row&7
  __shared__ alignas(16) char sV[2][8192];   // [d][t'] 128B rows, chunk ^= row&7
  int qb = gridDim.x - 1 - blockIdx.x;       // heavy tiles first
  int bh = blockIdx.y;
  int b = bh / Hz, h = bh - b*Hz;
  int tid = threadIdx.x, w = tid >> 6, l = tid & 63;
  int lr = l & 15, lg = l >> 4;
  const int q0 = qb*QBLK;
  const int qminw = q0 + w*16;
  const int qmaxw = qminw + 15;
  const int q_l = qminw + lr;

  const bf16* qbase = qws + ((size_t)bh*Tz + qminw + lr)*Dz + lg*8;
  bf16x8 qf0 = *(const bf16x8*)qbase;
  bf16x8 qf1 = *(const bf16x8*)(qbase + 32);

  f32x4 o[4] = {};
  float mrun = -1e30f, lrun = 0.f;

  const bf16* kgb = kb  + (size_t)bh*Tz*Dz;
  const bf16* vgb = vtb + (size_t)bh*Dz*Tz;

  int nT = 2*qb + 2;
  stageKV(kgb, vgb, 0, sK[0], sV[0], tid, w);
  int buf = 0;
  for (int kt = 0; kt + 1 < nT; ++kt) {
    stageKV(kgb, vgb, (kt + 1)*KVB, sK[buf ^ 1], sV[buf ^ 1], tid, w);
    asm volatile("s_waitcnt vmcnt(2)" ::: "memory");
    __builtin_amdgcn_s_barrier();
    __builtin_amdgcn_sched_barrier(0);
    attn_tile(kt*KVB, qminw, qmaxw, q_l, lr, lg, sK[buf], sV[buf],
              qf0, qf1, o, mrun, lrun);
    asm volatile("s_waitcnt lgkmcnt(0)" ::: "memory");
    __builtin_amdgcn_s_barrier();
    __builtin_amdgcn_sched_barrier(0);
    buf ^= 1;
  }
  asm volatile("s_waitcnt vmcnt(0)" ::: "memory");
  __builtin_amdgcn_s_barrier();
  __builtin_amdgcn_sched_barrier(0);
  attn_tile((nT - 1)*KVB, qminw, qmaxw, q_l, lr, lg, sK[buf], sV[buf],
            qf0, qf1, o, mrun, lrun);

  float inv = 1.0f / lrun;
  float i0 = __shfl(inv, 4*lg + 0);
  float i1 = __shfl(inv, 4*lg + 1);
  float i2 = __shfl(inv, 4*lg + 2);
  float i3 = __shfl(inv, 4*lg + 3);
  #pragma unroll
  for (int nd = 0; nd < 4; ++nd) {
    int d = nd*16 + lr;
    int t0 = q0 + w*16 + lg*4;
    bf16* yp = yatt + ((size_t)(b*Tz + t0))*Cz + h*Dz + d;
    yp[0*Cz]   = (bf16)(o[nd][0] * i0);
    yp[1*Cz]   = (bf16)(o[nd][1] * i1);
    yp[2*Cz]   = (bf16)(o[nd][2] * i2);
    yp[3*Cz]   = (bf16)(o[nd][3] * i3);
  }
}

// ---------------- launch ----------------
extern "C" void kernel_launch(void* const* d_in, const int* in_sizes, int n_in,
                              void* d_out, int out_size, void* d_ws, size_t ws_size,
                              hipStream_t stream) {
  const float* x      = (const float*)d_in[0];
  const float* w_attn = (const float*)d_in[1];
  const float* b_attn = (const float*)d_in[2];
  const float* w_proj = (const float*)d_in[3];
  const float* b_proj = (const float*)d_in[4];

  float* y    = (float*)d_out;
  float* kout = y + YSZ;
  float* vout = y + 2*YSZ;

  char* ws = (char*)d_ws;
  bf16* xb   = (bf16*)ws;                     // 25165824 B (reused as yatt)
  bf16* qws  = (bf16*)(ws + 25165824);        // 25165824 B
  bf16* kb   = (bf16*)(ws + 50331648);        // 25165824 B
  bf16* vtb  = (bf16*)(ws + 75497472);        // 25165824 B
  bf16* wtA  = (bf16*)(ws + 100663296);       // 3538944 B
  bf16* wtP  = (bf16*)(ws + 104202240);       // 1179648 B
  bf16* yatt = xb;

  prep_x<<<2048, 256, 0, stream>>>(x, xb);
  transpose_conv<<<dim3(N3/32, Cz/32), 256, 0, stream>>>(w_attn, wtA, Cz, N3);
  transpose_conv<<<dim3(Cz/32, Cz/32), 256, 0, stream>>>(w_proj, wtP, Cz, Cz);

  gemm128<0><<<dim3((Mz/128)*(N3/128)), 256, 0, stream>>>(
      xb, wtA, Cz, Mz/128, N3/128, b_attn, qws, kb, vtb, kout, vout, nullptr);

  attn128<<<dim3(Tz/QBLK, Bz*Hz), 512, 0, stream>>>(qws, kb, vtb, yatt);

  gemm128<1><<<dim3((Mz/128)*(Cz/128)), 256, 0, stream>>>(
      yatt, wtP, Cz, Mz/128, Cz/128, b_proj, nullptr, nullptr, nullptr,
      nullptr, nullptr, y);
}

// Round 9
// 384.550 us; speedup vs baseline: 1.7770x; 1.0266x over previous
//
#include <hip/hip_runtime.h>
#include <hip/hip_bf16.h>
#include <stdint.h>

#define Bz 8
#define Tz 2048
#define Cz 768
#define Hz 12
#define Dz 64
#define Mz (Bz*Tz)          // 16384
#define N3 (3*Cz)           // 2304
#define YSZ ((size_t)Mz*Cz) // 12582912

#define SCL 0.18033688011112042f  // log2(e) / sqrt(64)
#define KVB 64
#define QBLK 128

typedef __bf16 bf16;
typedef __attribute__((ext_vector_type(8))) bf16 bf16x8;
typedef __attribute__((ext_vector_type(4))) bf16 bf16x4;
typedef __attribute__((ext_vector_type(4))) float f32x4;

#define MFMA(A_,B_,C_) __builtin_amdgcn_mfma_f32_16x16x32_bf16(A_,B_,C_,0,0,0)

__device__ __forceinline__ void gll16(const void* g, void* l) {
  __builtin_amdgcn_global_load_lds(
      (const __attribute__((address_space(1))) void*)g,
      (__attribute__((address_space(3))) void*)l, 16, 0, 0);
}

// ---------------- prep: x fp32 -> bf16 ----------------
__global__ __launch_bounds__(256) void prep_x(const float* __restrict__ x,
                                              bf16* __restrict__ xb) {
  int i = blockIdx.x*blockDim.x + threadIdx.x;
  int stride = gridDim.x*blockDim.x;
  const float4* x4 = (const float4*)x;
  int n4 = (int)(YSZ/4);
  for (int j = i; j < n4; j += stride) {
    float4 f = x4[j];
    bf16x4 o = { (bf16)f.x, (bf16)f.y, (bf16)f.z, (bf16)f.w };
    *(bf16x4*)(xb + 4*(size_t)j) = o;
  }
}

// ---------------- prep: transpose+convert W [R][Ncol] f32 -> Wt [Ncol][R] bf16 ----------------
__global__ __launch_bounds__(256) void transpose_conv(const float* __restrict__ src,
                                                      bf16* __restrict__ dst,
                                                      int R, int Ncol) {
  __shared__ float tile[32][33];
  int bx = blockIdx.x, by = blockIdx.y;
  int tx = threadIdx.x & 31, ty = threadIdx.x >> 5;
  #pragma unroll
  for (int i = 0; i < 4; ++i)
    tile[ty + 8*i][tx] = src[(size_t)(by*32 + ty + 8*i)*Ncol + bx*32 + tx];
  __syncthreads();
  #pragma unroll
  for (int i = 0; i < 4; ++i)
    dst[(size_t)(bx*32 + ty + 8*i)*R + by*32 + tx] = (bf16)tile[tx][ty + 8*i];
}

// ---------------- GEMM: C[M,N] = A[M,K] * Bt[N,K]^T  (BK=64, swizzled LDS) ----------------
// EPI 0: qkv epilogue. q -> qws bf16 (pre-scaled); k -> kout f32 + kws bf16;
//        v -> vout f32 + vtb bf16 transposed [BH][D][T] with kv-permuted T axis.
// EPI 1: y = acc + bias (f32)
template<int EPI>
__global__ __launch_bounds__(256) void gemm128(
    const bf16* __restrict__ A, const bf16* __restrict__ Bt,
    int Kdim, int Mtiles, int Ntiles,
    const float* __restrict__ bias,
    bf16* __restrict__ qws, bf16* __restrict__ kws, bf16* __restrict__ vtb,
    float* __restrict__ kout, float* __restrict__ vout,
    float* __restrict__ yout)
{
  __shared__ alignas(16) bf16 sA[128*64];   // [row][64] 128B rows, chunk ^= row&7
  __shared__ alignas(16) bf16 sB[128*64];
  int nwg = Mtiles*Ntiles;
  int bid = blockIdx.x;
  int cpx = nwg >> 3;
  int swz = (bid & 7)*cpx + (bid >> 3);
  int mtile = swz % Mtiles, ntile = swz / Mtiles;
  int tid = threadIdx.x, w = tid >> 6, l = tid & 63;
  int wr = w >> 1, wc = w & 1;
  const int rowBase = mtile*128, colBase = ntile*128;

  f32x4 acc[4][4] = {};

  // staging: thread covers chunk ch of row rbase (+p*32), source pre-swizzled
  int rbase = tid >> 3;            // 0..31
  int ch    = tid & 7;
  int swk   = (ch ^ (rbase & 7)) << 3;   // element offset within row
  const bf16* gA = A + (size_t)(rowBase + rbase)*Kdim + swk;
  const bf16* gB = Bt + (size_t)(colBase + rbase)*Kdim + swk;
  char* lA = (char*)sA + w*1024;
  char* lB = (char*)sB + w*1024;

  int lr = l & 15, lg = l >> 4;

  for (int k0 = 0; k0 < Kdim; k0 += 64) {
    #pragma unroll
    for (int p = 0; p < 4; ++p) {
      gll16(gA + (size_t)(p*32)*Kdim, lA + p*4096);
      gll16(gB + (size_t)(p*32)*Kdim, lB + p*4096);
    }
    gA += 64; gB += 64;
    __syncthreads();
    #pragma unroll
    for (int kk = 0; kk < 2; ++kk) {
      bf16x8 af[4], bfr[4];
      int cc = ((kk*4 + lg) ^ (lr & 7)) << 4;
      #pragma unroll
      for (int m = 0; m < 4; ++m)
        af[m] = *(const bf16x8*)((const char*)sA + (wr*64 + m*16 + lr)*128 + cc);
      #pragma unroll
      for (int n = 0; n < 4; ++n)
        bfr[n] = *(const bf16x8*)((const char*)sB + (wc*64 + n*16 + lr)*128 + cc);
      #pragma unroll
      for (int m = 0; m < 4; ++m)
        #pragma unroll
        for (int n = 0; n < 4; ++n)
          acc[m][n] = MFMA(af[m], bfr[n], acc[m][n]);
    }
    __syncthreads();
  }

  #pragma unroll
  for (int m = 0; m < 4; ++m) {
    #pragma unroll
    for (int n = 0; n < 4; ++n) {
      int gcol = colBase + wc*64 + n*16 + lr;
      float bv = bias[gcol];
      int grow0 = rowBase + wr*64 + m*16 + lg*4;
      if (EPI == 1) {
        #pragma unroll
        for (int r = 0; r < 4; ++r)
          yout[(size_t)(grow0 + r)*Cz + gcol] = acc[m][n][r] + bv;
      } else {
        int which = gcol / Cz;               // uniform over r (16-col blocks)
        int within = gcol - which*Cz;
        int h = within >> 6, d = within & 63;
        int bidx = grow0 >> 11;              // same for r=0..3 (tile 128-aligned)
        int t0 = grow0 & 2047;
        size_t bhTD = ((size_t)bidx*Hz + h);
        if (which == 0) {
          bf16* qp = qws + (bhTD*Tz + t0)*Dz + d;
          #pragma unroll
          for (int r = 0; r < 4; ++r)
            qp[(size_t)r*Dz] = (bf16)((acc[m][n][r] + bv) * SCL);
        } else if (which == 1) {
          float* kp = kout + (bhTD*Tz + t0)*Dz + d;
          bf16*  kp2 = kws + (bhTD*Tz + t0)*Dz + d;
          #pragma unroll
          for (int r = 0; r < 4; ++r) {
            float v = acc[m][n][r] + bv;
            kp[(size_t)r*Dz] = v;
            kp2[(size_t)r*Dz] = (bf16)v;
          }
        } else {
          float* vp = vout + (bhTD*Tz + t0)*Dz + d;
          bf16x4 pk;
          #pragma unroll
          for (int r = 0; r < 4; ++r) {
            float v = acc[m][n][r] + bv;
            vp[(size_t)r*Dz] = v;
            pk[r] = (bf16)v;
          }
          // transposed + kv-permuted store: slot s in each 32-block holds
          // true kv = 16*((s>>2)&1) + 4*(s>>3) + (s&3); inverse applied here.
          int ts = (t0 & ~31) | (((t0 >> 2) & 3) << 3) | (((t0 >> 4) & 1) << 2) | (t0 & 3);
          *(bf16x4*)(vtb + (bhTD*Dz + d)*Tz + ts) = pk;
        }
      }
    }
  }
}

// ---------------- flash attention (causal), QBLK=128, 8 waves, KVB=64 ----------------
// Single barrier per tile: 3-deep LDS rotation, stage issued AFTER the barrier.
__device__ __forceinline__ void stageKV(const bf16* kgb, const bf16* vgb, int kv0,
                                        char* cK, char* cV, int tid, int w) {
  int off = tid*16;                 // 0..8191 over 512 threads
  int row = off >> 7, ch = (off >> 4) & 7;
  int sw = ((ch ^ (row & 7)) << 3);
  gll16(kgb + (size_t)(kv0 + row)*Dz + sw, cK + w*1024);
  gll16(vgb + (size_t)row*Tz + kv0 + sw,   cV + w*1024);
}

__device__ __forceinline__ void attn_tile(
    int kv0, int qminw, int qmaxw, int q_l, int lr, int lg,
    const char* cK, const char* cV,
    const bf16x8& qf0, const bf16x8& qf1,
    f32x4 (&o)[4], float& mrun, float& lrun)
{
  const f32x4 zf = {0.f, 0.f, 0.f, 0.f};
  f32x4 s[4];
  // S^T[kv][q] = K * Q^T (swapped): lane owns q=q_l, kv = kv0 + n*16 + 4*lg + r
  __builtin_amdgcn_s_setprio(1);
  #pragma unroll
  for (int n = 0; n < 4; ++n) {
    int kvb = kv0 + n*16;
    if (kvb <= qmaxw) {
      int row = n*16 + lr;
      int c0 = lg ^ (lr & 7);
      bf16x8 kf0 = *(const bf16x8*)(cK + row*128 + (c0 << 4));
      bf16x8 kf1 = *(const bf16x8*)(cK + row*128 + ((c0 ^ 4) << 4));
      f32x4 t = MFMA(kf0, qf0, zf);
      s[n] = MFMA(kf1, qf1, t);
    } else {
      s[n][0] = -1e30f; s[n][1] = -1e30f; s[n][2] = -1e30f; s[n][3] = -1e30f;
    }
  }
  __builtin_amdgcn_s_setprio(0);
  // causal mask (diag blocks only; scale pre-folded into Q)
  #pragma unroll
  for (int n = 0; n < 4; ++n) {
    int kvb = kv0 + n*16;
    if (kvb <= qmaxw && kvb + 15 > qminw) {
      #pragma unroll
      for (int r = 0; r < 4; ++r)
        s[n][r] = (kvb + 4*lg + r <= q_l) ? s[n][r] : -1e30f;
    }
  }
  // in-lane max tree + 2 shfl
  f32x4 a0;
  #pragma unroll
  for (int r = 0; r < 4; ++r)
    a0[r] = fmaxf(fmaxf(s[0][r], s[1][r]), fmaxf(s[2][r], s[3][r]));
  float mx = fmaxf(fmaxf(a0[0], a0[1]), fmaxf(a0[2], a0[3]));
  mx = fmaxf(mx, __shfl_xor(mx, 16));
  mx = fmaxf(mx, __shfl_xor(mx, 32));

  bool skip = __all(mx <= mrun + 8.0f);
  float corr = 1.0f;
  if (!skip) {
    float mnew = fmaxf(mrun, mx);
    corr = exp2f(mrun - mnew);
    mrun = mnew;
  }
  f32x4 acc4 = zf;
  #pragma unroll
  for (int n = 0; n < 4; ++n) {
    #pragma unroll
    for (int r = 0; r < 4; ++r) {
      float e = exp2f(s[n][r] - mrun);
      s[n][r] = e;
      acc4[r] += e;
    }
  }
  float rs = (acc4[0] + acc4[1]) + (acc4[2] + acc4[3]);
  rs += __shfl_xor(rs, 16);
  rs += __shfl_xor(rs, 32);
  if (!skip) {
    lrun = lrun*corr + rs;
    float c0_ = __shfl(corr, 4*lg + 0);
    float c1_ = __shfl(corr, 4*lg + 1);
    float c2_ = __shfl(corr, 4*lg + 2);
    float c3_ = __shfl(corr, 4*lg + 3);
    #pragma unroll
    for (int nd = 0; nd < 4; ++nd) {
      o[nd][0] *= c0_; o[nd][1] *= c1_; o[nd][2] *= c2_; o[nd][3] *= c3_;
    }
  } else {
    lrun += rs;
  }
  // O += P V : pf built fully in-lane (V kv-axis pre-permuted to match
  // ownership: slot 8*lg+e of 32-block kk holds kv = 16*(e>>2)+4*lg+(e&3))
  __builtin_amdgcn_s_setprio(1);
  #pragma unroll
  for (int kk = 0; kk < 2; ++kk) {
    if (kv0 + kk*32 <= qmaxw) {
      bf16x8 pf;
      pf[0] = (bf16)s[2*kk][0];   pf[1] = (bf16)s[2*kk][1];
      pf[2] = (bf16)s[2*kk][2];   pf[3] = (bf16)s[2*kk][3];
      pf[4] = (bf16)s[2*kk+1][0]; pf[5] = (bf16)s[2*kk+1][1];
      pf[6] = (bf16)s[2*kk+1][2]; pf[7] = (bf16)s[2*kk+1][3];
      int cb = (kk*4 + lg) ^ (lr & 7);
      #pragma unroll
      for (int nd = 0; nd < 4; ++nd) {
        bf16x8 vf = *(const bf16x8*)(cV + (nd*16 + lr)*128 + (cb << 4));
        o[nd] = MFMA(pf, vf, o[nd]);
      }
    }
  }
  __builtin_amdgcn_s_setprio(0);
}

__global__ __launch_bounds__(512, 6) void attn128(
    const bf16* __restrict__ qws, const bf16* __restrict__ kb,
    const bf16* __restrict__ vtb, bf16* __restrict__ yatt)
{
  __shared__ alignas(16) char sK[3][8192];   // [kv][d] 128B rows, chunk ^= row&7
  __shared__ alignas(16) char sV[3][8192];   // [d][t'] 128B rows, chunk ^= row&7
  int qb = gridDim.x - 1 - blockIdx.x;       // heavy tiles first
  int bh = blockIdx.y;
  int b = bh / Hz, h = bh - b*Hz;
  int tid = threadIdx.x, w = tid >> 6, l = tid & 63;
  int lr = l & 15, lg = l >> 4;
  const int q0 = qb*QBLK;
  const int qminw = q0 + w*16;
  const int qmaxw = qminw + 15;
  const int q_l = qminw + lr;

  const bf16* qbase = qws + ((size_t)bh*Tz + qminw + lr)*Dz + lg*8;
  bf16x8 qf0 = *(const bf16x8*)qbase;
  bf16x8 qf1 = *(const bf16x8*)(qbase + 32);

  f32x4 o[4] = {};
  float mrun = -1e30f, lrun = 0.f;

  const bf16* kgb = kb  + (size_t)bh*Tz*Dz;
  const bf16* vgb = vtb + (size_t)bh*Dz*Tz;

  int nT = 2*qb + 2;
  stageKV(kgb, vgb, 0,   sK[0], sV[0], tid, w);
  stageKV(kgb, vgb, KVB, sK[1], sV[1], tid, w);
  int cur = 0;
  for (int kt = 0; kt < nT; ++kt) {
    if (kt + 1 < nT) {
      asm volatile("s_waitcnt vmcnt(2) lgkmcnt(0)" ::: "memory");
    } else {
      asm volatile("s_waitcnt vmcnt(0) lgkmcnt(0)" ::: "memory");
    }
    __builtin_amdgcn_s_barrier();
    __builtin_amdgcn_sched_barrier(0);
    if (kt + 2 < nT) {
      int nb = cur + 2; if (nb >= 3) nb -= 3;
      stageKV(kgb, vgb, (kt + 2)*KVB, sK[nb], sV[nb], tid, w);
    }
    attn_tile(kt*KVB, qminw, qmaxw, q_l, lr, lg, sK[cur], sV[cur],
              qf0, qf1, o, mrun, lrun);
    if (++cur == 3) cur = 0;
  }

  float inv = 1.0f / lrun;
  float i0 = __shfl(inv, 4*lg + 0);
  float i1 = __shfl(inv, 4*lg + 1);
  float i2 = __shfl(inv, 4*lg + 2);
  float i3 = __shfl(inv, 4*lg + 3);
  #pragma unroll
  for (int nd = 0; nd < 4; ++nd) {
    int d = nd*16 + lr;
    int t0 = q0 + w*16 + lg*4;
    bf16* yp = yatt + ((size_t)(b*Tz + t0))*Cz + h*Dz + d;
    yp[0*Cz]   = (bf16)(o[nd][0] * i0);
    yp[1*Cz]   = (bf16)(o[nd][1] * i1);
    yp[2*Cz]   = (bf16)(o[nd][2] * i2);
    yp[3*Cz]   = (bf16)(o[nd][3] * i3);
  }
}

// ---------------- launch ----------------
extern "C" void kernel_launch(void* const* d_in, const int* in_sizes, int n_in,
                              void* d_out, int out_size, void* d_ws, size_t ws_size,
                              hipStream_t stream) {
  const float* x      = (const float*)d_in[0];
  const float* w_attn = (const float*)d_in[1];
  const float* b_attn = (const float*)d_in[2];
  const float* w_proj = (const float*)d_in[3];
  const float* b_proj = (const float*)d_in[4];

  float* y    = (float*)d_out;
  float* kout = y + YSZ;
  float* vout = y + 2*YSZ;

  char* ws = (char*)d_ws;
  bf16* xb   = (bf16*)ws;                     // 25165824 B (reused as yatt)
  bf16* qws  = (bf16*)(ws + 25165824);        // 25165824 B
  bf16* kb   = (bf16*)(ws + 50331648);        // 25165824 B
  bf16* vtb  = (bf16*)(ws + 75497472);        // 25165824 B
  bf16* wtA  = (bf16*)(ws + 100663296);       // 3538944 B
  bf16* wtP  = (bf16*)(ws + 104202240);       // 1179648 B
  bf16* yatt = xb;

  prep_x<<<2048, 256, 0, stream>>>(x, xb);
  transpose_conv<<<dim3(N3/32, Cz/32), 256, 0, stream>>>(w_attn, wtA, Cz, N3);
  transpose_conv<<<dim3(Cz/32, Cz/32), 256, 0, stream>>>(w_proj, wtP, Cz, Cz);

  gemm128<0><<<dim3((Mz/128)*(N3/128)), 256, 0, stream>>>(
      xb, wtA, Cz, Mz/128, N3/128, b_attn, qws, kb, vtb, kout, vout, nullptr);

  attn128<<<dim3(Tz/QBLK, Bz*Hz), 512, 0, stream>>>(qws, kb, vtb, yatt);

  gemm128<1><<<dim3((Mz/128)*(Cz/128)), 256, 0, stream>>>(
      yatt, wtP, Cz, Mz/128, Cz/128, b_proj, nullptr, nullptr, nullptr,
      nullptr, nullptr, y);
}

// Round 10
// 303.101 us; speedup vs baseline: 2.2546x; 1.2687x over previous
//
#include <hip/hip_runtime.h>
#include <hip/hip_bf16.h>
#include <stdint.h>

#define Bz 8
#define Tz 2048
#define Cz 768
#define Hz 12
#define Dz 64
#define Mz (Bz*Tz)          // 16384
#define N3 (3*Cz)           // 2304
#define YSZ ((size_t)Mz*Cz) // 12582912

#define SCL 0.18033688011112042f  // log2(e) / sqrt(64)
#define KVB 64
#define QBLK 128

typedef __bf16 bf16;
typedef __attribute__((ext_vector_type(8))) bf16 bf16x8;
typedef __attribute__((ext_vector_type(4))) bf16 bf16x4;
typedef __attribute__((ext_vector_type(4))) float f32x4;

#define MFMA(A_,B_,C_) __builtin_amdgcn_mfma_f32_16x16x32_bf16(A_,B_,C_,0,0,0)

__device__ __forceinline__ void gll16(const void* g, void* l) {
  __builtin_amdgcn_global_load_lds(
      (const __attribute__((address_space(1))) void*)g,
      (__attribute__((address_space(3))) void*)l, 16, 0, 0);
}

// ---------------- prep: x fp32 -> bf16 ----------------
__global__ __launch_bounds__(256) void prep_x(const float* __restrict__ x,
                                              bf16* __restrict__ xb) {
  int i = blockIdx.x*blockDim.x + threadIdx.x;
  int stride = gridDim.x*blockDim.x;
  const float4* x4 = (const float4*)x;
  int n4 = (int)(YSZ/4);
  for (int j = i; j < n4; j += stride) {
    float4 f = x4[j];
    bf16x4 o = { (bf16)f.x, (bf16)f.y, (bf16)f.z, (bf16)f.w };
    *(bf16x4*)(xb + 4*(size_t)j) = o;
  }
}

// ---------------- prep: transpose+convert W [R][Ncol] f32 -> Wt [Ncol][R] bf16 ----------------
__global__ __launch_bounds__(256) void transpose_conv(const float* __restrict__ src,
                                                      bf16* __restrict__ dst,
                                                      int R, int Ncol) {
  __shared__ float tile[32][33];
  int bx = blockIdx.x, by = blockIdx.y;
  int tx = threadIdx.x & 31, ty = threadIdx.x >> 5;
  #pragma unroll
  for (int i = 0; i < 4; ++i)
    tile[ty + 8*i][tx] = src[(size_t)(by*32 + ty + 8*i)*Ncol + bx*32 + tx];
  __syncthreads();
  #pragma unroll
  for (int i = 0; i < 4; ++i)
    dst[(size_t)(bx*32 + ty + 8*i)*R + by*32 + tx] = (bf16)tile[tx][ty + 8*i];
}

// ---------------- GEMM: C[M,N] = A[M,K] * Bt[N,K]^T  (BK=64, swizzled LDS) ----------------
// EPI 0: qkv epilogue. q -> qws bf16 (pre-scaled); k -> kout f32 + kws bf16;
//        v -> vout f32 + vtb bf16 transposed [BH][D][T] with kv-permuted T axis.
// EPI 1: y = acc + bias (f32)
template<int EPI>
__global__ __launch_bounds__(256) void gemm128(
    const bf16* __restrict__ A, const bf16* __restrict__ Bt,
    int Kdim, int Mtiles, int Ntiles,
    const float* __restrict__ bias,
    bf16* __restrict__ qws, bf16* __restrict__ kws, bf16* __restrict__ vtb,
    float* __restrict__ kout, float* __restrict__ vout,
    float* __restrict__ yout)
{
  __shared__ alignas(16) bf16 sA[128*64];   // [row][64] 128B rows, chunk ^= row&7
  __shared__ alignas(16) bf16 sB[128*64];
  int nwg = Mtiles*Ntiles;
  int bid = blockIdx.x;
  int cpx = nwg >> 3;
  int swz = (bid & 7)*cpx + (bid >> 3);
  int mtile = swz % Mtiles, ntile = swz / Mtiles;
  int tid = threadIdx.x, w = tid >> 6, l = tid & 63;
  int wr = w >> 1, wc = w & 1;
  const int rowBase = mtile*128, colBase = ntile*128;

  f32x4 acc[4][4] = {};

  // staging: thread covers chunk ch of row rbase (+p*32), source pre-swizzled
  int rbase = tid >> 3;            // 0..31
  int ch    = tid & 7;
  int swk   = (ch ^ (rbase & 7)) << 3;   // element offset within row
  const bf16* gA = A + (size_t)(rowBase + rbase)*Kdim + swk;
  const bf16* gB = Bt + (size_t)(colBase + rbase)*Kdim + swk;
  char* lA = (char*)sA + w*1024;
  char* lB = (char*)sB + w*1024;

  int lr = l & 15, lg = l >> 4;

  for (int k0 = 0; k0 < Kdim; k0 += 64) {
    #pragma unroll
    for (int p = 0; p < 4; ++p) {
      gll16(gA + (size_t)(p*32)*Kdim, lA + p*4096);
      gll16(gB + (size_t)(p*32)*Kdim, lB + p*4096);
    }
    gA += 64; gB += 64;
    __syncthreads();
    #pragma unroll
    for (int kk = 0; kk < 2; ++kk) {
      bf16x8 af[4], bfr[4];
      int cc = ((kk*4 + lg) ^ (lr & 7)) << 4;
      #pragma unroll
      for (int m = 0; m < 4; ++m)
        af[m] = *(const bf16x8*)((const char*)sA + (wr*64 + m*16 + lr)*128 + cc);
      #pragma unroll
      for (int n = 0; n < 4; ++n)
        bfr[n] = *(const bf16x8*)((const char*)sB + (wc*64 + n*16 + lr)*128 + cc);
      #pragma unroll
      for (int m = 0; m < 4; ++m)
        #pragma unroll
        for (int n = 0; n < 4; ++n)
          acc[m][n] = MFMA(af[m], bfr[n], acc[m][n]);
    }
    __syncthreads();
  }

  #pragma unroll
  for (int m = 0; m < 4; ++m) {
    #pragma unroll
    for (int n = 0; n < 4; ++n) {
      int gcol = colBase + wc*64 + n*16 + lr;
      float bv = bias[gcol];
      int grow0 = rowBase + wr*64 + m*16 + lg*4;
      if (EPI == 1) {
        #pragma unroll
        for (int r = 0; r < 4; ++r)
          yout[(size_t)(grow0 + r)*Cz + gcol] = acc[m][n][r] + bv;
      } else {
        int which = gcol / Cz;               // uniform over r (16-col blocks)
        int within = gcol - which*Cz;
        int h = within >> 6, d = within & 63;
        int bidx = grow0 >> 11;              // same for r=0..3 (tile 128-aligned)
        int t0 = grow0 & 2047;
        size_t bhTD = ((size_t)bidx*Hz + h);
        if (which == 0) {
          bf16* qp = qws + (bhTD*Tz + t0)*Dz + d;
          #pragma unroll
          for (int r = 0; r < 4; ++r)
            qp[(size_t)r*Dz] = (bf16)((acc[m][n][r] + bv) * SCL);
        } else if (which == 1) {
          float* kp = kout + (bhTD*Tz + t0)*Dz + d;
          bf16*  kp2 = kws + (bhTD*Tz + t0)*Dz + d;
          #pragma unroll
          for (int r = 0; r < 4; ++r) {
            float v = acc[m][n][r] + bv;
            kp[(size_t)r*Dz] = v;
            kp2[(size_t)r*Dz] = (bf16)v;
          }
        } else {
          float* vp = vout + (bhTD*Tz + t0)*Dz + d;
          bf16x4 pk;
          #pragma unroll
          for (int r = 0; r < 4; ++r) {
            float v = acc[m][n][r] + bv;
            vp[(size_t)r*Dz] = v;
            pk[r] = (bf16)v;
          }
          // transposed + kv-permuted store: slot s in each 32-block holds
          // true kv = 16*((s>>2)&1) + 4*(s>>3) + (s&3); inverse applied here.
          int ts = (t0 & ~31) | (((t0 >> 2) & 3) << 3) | (((t0 >> 4) & 1) << 2) | (t0 & 3);
          *(bf16x4*)(vtb + (bhTD*Dz + d)*Tz + ts) = pk;
        }
      }
    }
  }
}

// ---------------- flash attention (causal), QBLK=128, 8 waves, KVB=64 ----------------
__device__ __forceinline__ void stageKV(const bf16* kgb, const bf16* vgb, int kv0,
                                        char* cK, char* cV, int tid, int w) {
  int off = tid*16;                 // 0..8191 over 512 threads
  int row = off >> 7, ch = (off >> 4) & 7;
  int sw = ((ch ^ (row & 7)) << 3);
  gll16(kgb + (size_t)(kv0 + row)*Dz + sw, cK + w*1024);
  gll16(vgb + (size_t)row*Tz + kv0 + sw,   cV + w*1024);
}

__device__ __forceinline__ void attn_tile(
    int kv0, int qminw, int qmaxw, int q_l, int lr, int lg,
    const char* cK, const char* cV,
    const bf16x8& qf0, const bf16x8& qf1,
    f32x4 (&o)[4], float& mrun, float& lrun)
{
  const f32x4 zf = {0.f, 0.f, 0.f, 0.f};
  f32x4 s[4];
  // S^T[kv][q] = K * Q^T (swapped): lane owns q=q_l, kv = kv0 + n*16 + 4*lg + r
  __builtin_amdgcn_s_setprio(1);
  #pragma unroll
  for (int n = 0; n < 4; ++n) {
    int kvb = kv0 + n*16;
    if (kvb <= qmaxw) {
      int row = n*16 + lr;
      int c0 = lg ^ (lr & 7);
      bf16x8 kf0 = *(const bf16x8*)(cK + row*128 + (c0 << 4));
      bf16x8 kf1 = *(const bf16x8*)(cK + row*128 + ((c0 ^ 4) << 4));
      f32x4 t = MFMA(kf0, qf0, zf);
      s[n] = MFMA(kf1, qf1, t);
    } else {
      s[n][0] = -1e30f; s[n][1] = -1e30f; s[n][2] = -1e30f; s[n][3] = -1e30f;
    }
  }
  __builtin_amdgcn_s_setprio(0);
  // causal mask (diag blocks only; scale pre-folded into Q)
  #pragma unroll
  for (int n = 0; n < 4; ++n) {
    int kvb = kv0 + n*16;
    if (kvb <= qmaxw && kvb + 15 > qminw) {
      #pragma unroll
      for (int r = 0; r < 4; ++r)
        s[n][r] = (kvb + 4*lg + r <= q_l) ? s[n][r] : -1e30f;
    }
  }
  // in-lane max tree + 2 shfl
  f32x4 a0;
  #pragma unroll
  for (int r = 0; r < 4; ++r)
    a0[r] = fmaxf(fmaxf(s[0][r], s[1][r]), fmaxf(s[2][r], s[3][r]));
  float mx = fmaxf(fmaxf(a0[0], a0[1]), fmaxf(a0[2], a0[3]));
  mx = fmaxf(mx, __shfl_xor(mx, 16));
  mx = fmaxf(mx, __shfl_xor(mx, 32));

  bool skip = __all(mx <= mrun + 8.0f);
  float corr = 1.0f;
  if (!skip) {
    float mnew = fmaxf(mrun, mx);
    corr = exp2f(mrun - mnew);
    mrun = mnew;
  }
  f32x4 acc4 = zf;
  #pragma unroll
  for (int n = 0; n < 4; ++n) {
    #pragma unroll
    for (int r = 0; r < 4; ++r) {
      float e = exp2f(s[n][r] - mrun);
      s[n][r] = e;
      acc4[r] += e;
    }
  }
  float rs = (acc4[0] + acc4[1]) + (acc4[2] + acc4[3]);
  rs += __shfl_xor(rs, 16);
  rs += __shfl_xor(rs, 32);
  if (!skip) {
    lrun = lrun*corr + rs;
    float c0_ = __shfl(corr, 4*lg + 0);
    float c1_ = __shfl(corr, 4*lg + 1);
    float c2_ = __shfl(corr, 4*lg + 2);
    float c3_ = __shfl(corr, 4*lg + 3);
    #pragma unroll
    for (int nd = 0; nd < 4; ++nd) {
      o[nd][0] *= c0_; o[nd][1] *= c1_; o[nd][2] *= c2_; o[nd][3] *= c3_;
    }
  } else {
    lrun += rs;
  }
  // O += P V : pf built fully in-lane (V kv-axis pre-permuted to match
  // ownership: slot 8*lg+e of 32-block kk holds kv = 16*(e>>2)+4*lg+(e&3))
  __builtin_amdgcn_s_setprio(1);
  #pragma unroll
  for (int kk = 0; kk < 2; ++kk) {
    if (kv0 + kk*32 <= qmaxw) {
      bf16x8 pf;
      pf[0] = (bf16)s[2*kk][0];   pf[1] = (bf16)s[2*kk][1];
      pf[2] = (bf16)s[2*kk][2];   pf[3] = (bf16)s[2*kk][3];
      pf[4] = (bf16)s[2*kk+1][0]; pf[5] = (bf16)s[2*kk+1][1];
      pf[6] = (bf16)s[2*kk+1][2]; pf[7] = (bf16)s[2*kk+1][3];
      int cb = (kk*4 + lg) ^ (lr & 7);
      #pragma unroll
      for (int nd = 0; nd < 4; ++nd) {
        bf16x8 vf = *(const bf16x8*)(cV + (nd*16 + lr)*128 + (cb << 4));
        o[nd] = MFMA(pf, vf, o[nd]);
      }
    }
  }
  __builtin_amdgcn_s_setprio(0);
}

__global__ __launch_bounds__(512, 6) void attn128(
    const bf16* __restrict__ qws, const bf16* __restrict__ kb,
    const bf16* __restrict__ vtb, bf16* __restrict__ yatt)
{
  __shared__ alignas(16) char sK[2][8192];   // [kv][d] 128B rows, chunk ^= row&7
  __shared__ alignas(16) char sV[2][8192];   // [d][t'] 128B rows, chunk ^= row&7
  // Global LPT order: heaviest q-tiles dispatch first across ALL bh.
  int bid = blockIdx.x;
  int qb = (Tz/QBLK) - 1 - bid/(Bz*Hz);
  int bh = bid % (Bz*Hz);
  int b = bh / Hz, h = bh - b*Hz;
  int tid = threadIdx.x, w = tid >> 6, l = tid & 63;
  int lr = l & 15, lg = l >> 4;
  const int q0 = qb*QBLK;
  const int qminw = q0 + w*16;
  const int qmaxw = qminw + 15;
  const int q_l = qminw + lr;

  const bf16* qbase = qws + ((size_t)bh*Tz + qminw + lr)*Dz + lg*8;
  bf16x8 qf0 = *(const bf16x8*)qbase;
  bf16x8 qf1 = *(const bf16x8*)(qbase + 32);

  f32x4 o[4] = {};
  float mrun = -1e30f, lrun = 0.f;

  const bf16* kgb = kb  + (size_t)bh*Tz*Dz;
  const bf16* vgb = vtb + (size_t)bh*Dz*Tz;

  int nT = 2*qb + 2;
  stageKV(kgb, vgb, 0, sK[0], sV[0], tid, w);
  int buf = 0;
  for (int kt = 0; kt + 1 < nT; ++kt) {
    stageKV(kgb, vgb, (kt + 1)*KVB, sK[buf ^ 1], sV[buf ^ 1], tid, w);
    asm volatile("s_waitcnt vmcnt(2)" ::: "memory");
    __builtin_amdgcn_s_barrier();
    __builtin_amdgcn_sched_barrier(0);
    attn_tile(kt*KVB, qminw, qmaxw, q_l, lr, lg, sK[buf], sV[buf],
              qf0, qf1, o, mrun, lrun);
    asm volatile("s_waitcnt lgkmcnt(0)" ::: "memory");
    __builtin_amdgcn_s_barrier();
    __builtin_amdgcn_sched_barrier(0);
    buf ^= 1;
  }
  asm volatile("s_waitcnt vmcnt(0)" ::: "memory");
  __builtin_amdgcn_s_barrier();
  __builtin_amdgcn_sched_barrier(0);
  attn_tile((nT - 1)*KVB, qminw, qmaxw, q_l, lr, lg, sK[buf], sV[buf],
            qf0, qf1, o, mrun, lrun);

  float inv = 1.0f / lrun;
  float i0 = __shfl(inv, 4*lg + 0);
  float i1 = __shfl(inv, 4*lg + 1);
  float i2 = __shfl(inv, 4*lg + 2);
  float i3 = __shfl(inv, 4*lg + 3);
  #pragma unroll
  for (int nd = 0; nd < 4; ++nd) {
    int d = nd*16 + lr;
    int t0 = q0 + w*16 + lg*4;
    bf16* yp = yatt + ((size_t)(b*Tz + t0))*Cz + h*Dz + d;
    yp[0*Cz]   = (bf16)(o[nd][0] * i0);
    yp[1*Cz]   = (bf16)(o[nd][1] * i1);
    yp[2*Cz]   = (bf16)(o[nd][2] * i2);
    yp[3*Cz]   = (bf16)(o[nd][3] * i3);
  }
}

// ---------------- launch ----------------
extern "C" void kernel_launch(void* const* d_in, const int* in_sizes, int n_in,
                              void* d_out, int out_size, void* d_ws, size_t ws_size,
                              hipStream_t stream) {
  const float* x      = (const float*)d_in[0];
  const float* w_attn = (const float*)d_in[1];
  const float* b_attn = (const float*)d_in[2];
  const float* w_proj = (const float*)d_in[3];
  const float* b_proj = (const float*)d_in[4];

  float* y    = (float*)d_out;
  float* kout = y + YSZ;
  float* vout = y + 2*YSZ;

  char* ws = (char*)d_ws;
  bf16* xb   = (bf16*)ws;                     // 25165824 B (reused as yatt)
  bf16* qws  = (bf16*)(ws + 25165824);        // 25165824 B
  bf16* kb   = (bf16*)(ws + 50331648);        // 25165824 B
  bf16* vtb  = (bf16*)(ws + 75497472);        // 25165824 B
  bf16* wtA  = (bf16*)(ws + 100663296);       // 3538944 B
  bf16* wtP  = (bf16*)(ws + 104202240);       // 1179648 B
  bf16* yatt = xb;

  prep_x<<<2048, 256, 0, stream>>>(x, xb);
  transpose_conv<<<dim3(N3/32, Cz/32), 256, 0, stream>>>(w_attn, wtA, Cz, N3);
  transpose_conv<<<dim3(Cz/32, Cz/32), 256, 0, stream>>>(w_proj, wtP, Cz, Cz);

  gemm128<0><<<dim3((Mz/128)*(N3/128)), 256, 0, stream>>>(
      xb, wtA, Cz, Mz/128, N3/128, b_attn, qws, kb, vtb, kout, vout, nullptr);

  attn128<<<dim3((Tz/QBLK)*(Bz*Hz)), 512, 0, stream>>>(qws, kb, vtb, yatt);

  gemm128<1><<<dim3((Mz/128)*(Cz/128)), 256, 0, stream>>>(
      yatt, wtP, Cz, Mz/128, Cz/128, b_proj, nullptr, nullptr, nullptr,
      nullptr, nullptr, y);
}

// Round 11
// 261.458 us; speedup vs baseline: 2.6136x; 1.1593x over previous
//
#include <hip/hip_runtime.h>
#include <hip/hip_bf16.h>
#include <stdint.h>

#define Bz 8
#define Tz 2048
#define Cz 768
#define Hz 12
#define Dz 64
#define Mz (Bz*Tz)          // 16384
#define N3 (3*Cz)           // 2304
#define YSZ ((size_t)Mz*Cz) // 12582912

#define SCL 0.18033688011112042f  // log2(e) / sqrt(64)
#define KVB 64
#define QBLK 128

typedef __bf16 bf16;
typedef __attribute__((ext_vector_type(8))) bf16 bf16x8;
typedef __attribute__((ext_vector_type(4))) bf16 bf16x4;
typedef __attribute__((ext_vector_type(4))) float f32x4;

#define MFMA(A_,B_,C_) __builtin_amdgcn_mfma_f32_16x16x32_bf16(A_,B_,C_,0,0,0)

__device__ __forceinline__ void gll16(const void* g, void* l) {
  __builtin_amdgcn_global_load_lds(
      (const __attribute__((address_space(1))) void*)g,
      (__attribute__((address_space(3))) void*)l, 16, 0, 0);
}

// ---------------- prep: x fp32 -> bf16 ----------------
__global__ __launch_bounds__(256) void prep_x(const float* __restrict__ x,
                                              bf16* __restrict__ xb) {
  int i = blockIdx.x*blockDim.x + threadIdx.x;
  int stride = gridDim.x*blockDim.x;
  const float4* x4 = (const float4*)x;
  int n4 = (int)(YSZ/4);
  for (int j = i; j < n4; j += stride) {
    float4 f = x4[j];
    bf16x4 o = { (bf16)f.x, (bf16)f.y, (bf16)f.z, (bf16)f.w };
    *(bf16x4*)(xb + 4*(size_t)j) = o;
  }
}

// ---------------- prep: transpose+convert W [R][Ncol] f32 -> Wt [Ncol][R] bf16 ----------------
__global__ __launch_bounds__(256) void transpose_conv(const float* __restrict__ src,
                                                      bf16* __restrict__ dst,
                                                      int R, int Ncol) {
  __shared__ float tile[32][33];
  int bx = blockIdx.x, by = blockIdx.y;
  int tx = threadIdx.x & 31, ty = threadIdx.x >> 5;
  #pragma unroll
  for (int i = 0; i < 4; ++i)
    tile[ty + 8*i][tx] = src[(size_t)(by*32 + ty + 8*i)*Ncol + bx*32 + tx];
  __syncthreads();
  #pragma unroll
  for (int i = 0; i < 4; ++i)
    dst[(size_t)(bx*32 + ty + 8*i)*R + by*32 + tx] = (bf16)tile[tx][ty + 8*i];
}

// ---------------- GEMM: C[M,N] = A[M,K] * Bt[N,K]^T  (BK=64, dbuf, swizzled LDS) ----------------
// EPI 0: qkv epilogue. q -> qws bf16 (pre-scaled); k -> kout f32 + kws bf16;
//        v -> vout f32 + vtb bf16 transposed [BH][D][T] with kv-permuted T axis.
// EPI 1: y = acc + bias (f32)
template<int EPI>
__global__ __launch_bounds__(256) void gemm128(
    const bf16* __restrict__ A, const bf16* __restrict__ Bt,
    int Kdim, int Mtiles, int Ntiles,
    const float* __restrict__ bias,
    bf16* __restrict__ qws, bf16* __restrict__ kws, bf16* __restrict__ vtb,
    float* __restrict__ kout, float* __restrict__ vout,
    float* __restrict__ yout)
{
  __shared__ alignas(16) bf16 sA[2][128*64];   // [row][64] 128B rows, chunk ^= row&7
  __shared__ alignas(16) bf16 sB[2][128*64];
  int nwg = Mtiles*Ntiles;
  int bid = blockIdx.x;
  int cpx = nwg >> 3;
  int swz = (bid & 7)*cpx + (bid >> 3);
  // ntile fast-varying: each XCD's contiguous range covers few M-tiles x all N-tiles
  int ntile = swz % Ntiles, mtile = swz / Ntiles;
  int tid = threadIdx.x, w = tid >> 6, l = tid & 63;
  int wr = w >> 1, wc = w & 1;
  const int rowBase = mtile*128, colBase = ntile*128;

  f32x4 acc[4][4] = {};

  // staging: thread covers chunk ch of row rbase (+p*32), source pre-swizzled
  int rbase = tid >> 3;            // 0..31
  int ch    = tid & 7;
  int swk   = (ch ^ (rbase & 7)) << 3;   // element offset within row
  const bf16* gA = A + (size_t)(rowBase + rbase)*Kdim + swk;
  const bf16* gB = Bt + (size_t)(colBase + rbase)*Kdim + swk;

  int lr = l & 15, lg = l >> 4;
  int nK = Kdim >> 6;

  // prologue: stage tile 0 into buf 0
  {
    char* lA = (char*)sA[0] + w*1024;
    char* lB = (char*)sB[0] + w*1024;
    #pragma unroll
    for (int p = 0; p < 4; ++p) {
      gll16(gA + (size_t)(p*32)*Kdim, lA + p*4096);
      gll16(gB + (size_t)(p*32)*Kdim, lB + p*4096);
    }
    gA += 64; gB += 64;
  }
  int buf = 0;
  for (int t = 0; t < nK; ++t) {
    if (t + 1 < nK) {
      char* lA = (char*)sA[buf ^ 1] + w*1024;
      char* lB = (char*)sB[buf ^ 1] + w*1024;
      #pragma unroll
      for (int p = 0; p < 4; ++p) {
        gll16(gA + (size_t)(p*32)*Kdim, lA + p*4096);
        gll16(gB + (size_t)(p*32)*Kdim, lB + p*4096);
      }
      gA += 64; gB += 64;
      asm volatile("s_waitcnt vmcnt(8)" ::: "memory");
    } else {
      asm volatile("s_waitcnt vmcnt(0)" ::: "memory");
    }
    __builtin_amdgcn_s_barrier();
    __builtin_amdgcn_sched_barrier(0);
    const char* cA = (const char*)sA[buf];
    const char* cB = (const char*)sB[buf];
    __builtin_amdgcn_s_setprio(1);
    #pragma unroll
    for (int kk = 0; kk < 2; ++kk) {
      bf16x8 af[4], bfr[4];
      int cc = ((kk*4 + lg) ^ (lr & 7)) << 4;
      #pragma unroll
      for (int m = 0; m < 4; ++m)
        af[m] = *(const bf16x8*)(cA + (wr*64 + m*16 + lr)*128 + cc);
      #pragma unroll
      for (int n = 0; n < 4; ++n)
        bfr[n] = *(const bf16x8*)(cB + (wc*64 + n*16 + lr)*128 + cc);
      #pragma unroll
      for (int m = 0; m < 4; ++m)
        #pragma unroll
        for (int n = 0; n < 4; ++n)
          acc[m][n] = MFMA(af[m], bfr[n], acc[m][n]);
    }
    __builtin_amdgcn_s_setprio(0);
    asm volatile("s_waitcnt lgkmcnt(0)" ::: "memory");
    __builtin_amdgcn_s_barrier();
    __builtin_amdgcn_sched_barrier(0);
    buf ^= 1;
  }

  #pragma unroll
  for (int m = 0; m < 4; ++m) {
    #pragma unroll
    for (int n = 0; n < 4; ++n) {
      int gcol = colBase + wc*64 + n*16 + lr;
      float bv = bias[gcol];
      int grow0 = rowBase + wr*64 + m*16 + lg*4;
      if (EPI == 1) {
        #pragma unroll
        for (int r = 0; r < 4; ++r)
          yout[(size_t)(grow0 + r)*Cz + gcol] = acc[m][n][r] + bv;
      } else {
        int which = gcol / Cz;               // uniform over r (16-col blocks)
        int within = gcol - which*Cz;
        int h = within >> 6, d = within & 63;
        int bidx = grow0 >> 11;              // same for r=0..3 (tile 128-aligned)
        int t0 = grow0 & 2047;
        size_t bhTD = ((size_t)bidx*Hz + h);
        if (which == 0) {
          bf16* qp = qws + (bhTD*Tz + t0)*Dz + d;
          #pragma unroll
          for (int r = 0; r < 4; ++r)
            qp[(size_t)r*Dz] = (bf16)((acc[m][n][r] + bv) * SCL);
        } else if (which == 1) {
          float* kp = kout + (bhTD*Tz + t0)*Dz + d;
          bf16*  kp2 = kws + (bhTD*Tz + t0)*Dz + d;
          #pragma unroll
          for (int r = 0; r < 4; ++r) {
            float v = acc[m][n][r] + bv;
            kp[(size_t)r*Dz] = v;
            kp2[(size_t)r*Dz] = (bf16)v;
          }
        } else {
          float* vp = vout + (bhTD*Tz + t0)*Dz + d;
          bf16x4 pk;
          #pragma unroll
          for (int r = 0; r < 4; ++r) {
            float v = acc[m][n][r] + bv;
            vp[(size_t)r*Dz] = v;
            pk[r] = (bf16)v;
          }
          // transposed + kv-permuted store: slot s in each 32-block holds
          // true kv = 16*((s>>2)&1) + 4*(s>>3) + (s&3); inverse applied here.
          int ts = (t0 & ~31) | (((t0 >> 2) & 3) << 3) | (((t0 >> 4) & 1) << 2) | (t0 & 3);
          *(bf16x4*)(vtb + (bhTD*Dz + d)*Tz + ts) = pk;
        }
      }
    }
  }
}

// ---------------- flash attention (causal), QBLK=128, 8 waves, KVB=64 ----------------
__device__ __forceinline__ void stageKV(const bf16* kgb, const bf16* vgb, int kv0,
                                        char* cK, char* cV, int tid, int w) {
  int off = tid*16;                 // 0..8191 over 512 threads
  int row = off >> 7, ch = (off >> 4) & 7;
  int sw = ((ch ^ (row & 7)) << 3);
  gll16(kgb + (size_t)(kv0 + row)*Dz + sw, cK + w*1024);
  gll16(vgb + (size_t)row*Tz + kv0 + sw,   cV + w*1024);
}

__device__ __forceinline__ void attn_tile(
    int kv0, int qminw, int qmaxw, int q_l, int lr, int lg,
    const char* cK, const char* cV,
    const bf16x8& qf0, const bf16x8& qf1,
    f32x4 (&o)[4], float& mrun, float& lrun)
{
  const f32x4 zf = {0.f, 0.f, 0.f, 0.f};
  f32x4 s[4];
  // S^T[kv][q] = K * Q^T (swapped): lane owns q=q_l, kv = kv0 + n*16 + 4*lg + r
  __builtin_amdgcn_s_setprio(1);
  #pragma unroll
  for (int n = 0; n < 4; ++n) {
    int kvb = kv0 + n*16;
    if (kvb <= qmaxw) {
      int row = n*16 + lr;
      int c0 = lg ^ (lr & 7);
      bf16x8 kf0 = *(const bf16x8*)(cK + row*128 + (c0 << 4));
      bf16x8 kf1 = *(const bf16x8*)(cK + row*128 + ((c0 ^ 4) << 4));
      f32x4 t = MFMA(kf0, qf0, zf);
      s[n] = MFMA(kf1, qf1, t);
    } else {
      s[n][0] = -1e30f; s[n][1] = -1e30f; s[n][2] = -1e30f; s[n][3] = -1e30f;
    }
  }
  __builtin_amdgcn_s_setprio(0);
  // causal mask (diag blocks only; scale pre-folded into Q)
  #pragma unroll
  for (int n = 0; n < 4; ++n) {
    int kvb = kv0 + n*16;
    if (kvb <= qmaxw && kvb + 15 > qminw) {
      #pragma unroll
      for (int r = 0; r < 4; ++r)
        s[n][r] = (kvb + 4*lg + r <= q_l) ? s[n][r] : -1e30f;
    }
  }
  // in-lane max tree + 2 shfl
  f32x4 a0;
  #pragma unroll
  for (int r = 0; r < 4; ++r)
    a0[r] = fmaxf(fmaxf(s[0][r], s[1][r]), fmaxf(s[2][r], s[3][r]));
  float mx = fmaxf(fmaxf(a0[0], a0[1]), fmaxf(a0[2], a0[3]));
  mx = fmaxf(mx, __shfl_xor(mx, 16));
  mx = fmaxf(mx, __shfl_xor(mx, 32));

  bool skip = __all(mx <= mrun + 8.0f);
  float corr = 1.0f;
  if (!skip) {
    float mnew = fmaxf(mrun, mx);
    corr = exp2f(mrun - mnew);
    mrun = mnew;
  }
  f32x4 acc4 = zf;
  #pragma unroll
  for (int n = 0; n < 4; ++n) {
    #pragma unroll
    for (int r = 0; r < 4; ++r) {
      float e = exp2f(s[n][r] - mrun);
      s[n][r] = e;
      acc4[r] += e;
    }
  }
  float rs = (acc4[0] + acc4[1]) + (acc4[2] + acc4[3]);
  rs += __shfl_xor(rs, 16);
  rs += __shfl_xor(rs, 32);
  if (!skip) {
    lrun = lrun*corr + rs;
    float c0_ = __shfl(corr, 4*lg + 0);
    float c1_ = __shfl(corr, 4*lg + 1);
    float c2_ = __shfl(corr, 4*lg + 2);
    float c3_ = __shfl(corr, 4*lg + 3);
    #pragma unroll
    for (int nd = 0; nd < 4; ++nd) {
      o[nd][0] *= c0_; o[nd][1] *= c1_; o[nd][2] *= c2_; o[nd][3] *= c3_;
    }
  } else {
    lrun += rs;
  }
  // O += P V : pf built fully in-lane (V kv-axis pre-permuted to match
  // ownership: slot 8*lg+e of 32-block kk holds kv = 16*(e>>2)+4*lg+(e&3))
  __builtin_amdgcn_s_setprio(1);
  #pragma unroll
  for (int kk = 0; kk < 2; ++kk) {
    if (kv0 + kk*32 <= qmaxw) {
      bf16x8 pf;
      pf[0] = (bf16)s[2*kk][0];   pf[1] = (bf16)s[2*kk][1];
      pf[2] = (bf16)s[2*kk][2];   pf[3] = (bf16)s[2*kk][3];
      pf[4] = (bf16)s[2*kk+1][0]; pf[5] = (bf16)s[2*kk+1][1];
      pf[6] = (bf16)s[2*kk+1][2]; pf[7] = (bf16)s[2*kk+1][3];
      int cb = (kk*4 + lg) ^ (lr & 7);
      #pragma unroll
      for (int nd = 0; nd < 4; ++nd) {
        bf16x8 vf = *(const bf16x8*)(cV + (nd*16 + lr)*128 + (cb << 4));
        o[nd] = MFMA(pf, vf, o[nd]);
      }
    }
  }
  __builtin_amdgcn_s_setprio(0);
}

__global__ __launch_bounds__(512, 6) void attn128(
    const bf16* __restrict__ qws, const bf16* __restrict__ kb,
    const bf16* __restrict__ vtb, bf16* __restrict__ yatt)
{
  __shared__ alignas(16) char sK[2][8192];   // [kv][d] 128B rows, chunk ^= row&7
  __shared__ alignas(16) char sV[2][8192];   // [d][t'] 128B rows, chunk ^= row&7
  // Global LPT order: heaviest q-tiles dispatch first across ALL bh.
  int bid = blockIdx.x;
  int qb = (Tz/QBLK) - 1 - bid/(Bz*Hz);
  int bh = bid % (Bz*Hz);
  int b = bh / Hz, h = bh - b*Hz;
  int tid = threadIdx.x, w = tid >> 6, l = tid & 63;
  int lr = l & 15, lg = l >> 4;
  const int q0 = qb*QBLK;
  const int qminw = q0 + w*16;
  const int qmaxw = qminw + 15;
  const int q_l = qminw + lr;

  const bf16* qbase = qws + ((size_t)bh*Tz + qminw + lr)*Dz + lg*8;
  bf16x8 qf0 = *(const bf16x8*)qbase;
  bf16x8 qf1 = *(const bf16x8*)(qbase + 32);

  f32x4 o[4] = {};
  float mrun = -1e30f, lrun = 0.f;

  const bf16* kgb = kb  + (size_t)bh*Tz*Dz;
  const bf16* vgb = vtb + (size_t)bh*Dz*Tz;

  int nT = 2*qb + 2;
  stageKV(kgb, vgb, 0, sK[0], sV[0], tid, w);
  int buf = 0;
  for (int kt = 0; kt + 1 < nT; ++kt) {
    stageKV(kgb, vgb, (kt + 1)*KVB, sK[buf ^ 1], sV[buf ^ 1], tid, w);
    asm volatile("s_waitcnt vmcnt(2)" ::: "memory");
    __builtin_amdgcn_s_barrier();
    __builtin_amdgcn_sched_barrier(0);
    attn_tile(kt*KVB, qminw, qmaxw, q_l, lr, lg, sK[buf], sV[buf],
              qf0, qf1, o, mrun, lrun);
    asm volatile("s_waitcnt lgkmcnt(0)" ::: "memory");
    __builtin_amdgcn_s_barrier();
    __builtin_amdgcn_sched_barrier(0);
    buf ^= 1;
  }
  asm volatile("s_waitcnt vmcnt(0)" ::: "memory");
  __builtin_amdgcn_s_barrier();
  __builtin_amdgcn_sched_barrier(0);
  attn_tile((nT - 1)*KVB, qminw, qmaxw, q_l, lr, lg, sK[buf], sV[buf],
            qf0, qf1, o, mrun, lrun);

  float inv = 1.0f / lrun;
  float i0 = __shfl(inv, 4*lg + 0);
  float i1 = __shfl(inv, 4*lg + 1);
  float i2 = __shfl(inv, 4*lg + 2);
  float i3 = __shfl(inv, 4*lg + 3);
  #pragma unroll
  for (int nd = 0; nd < 4; ++nd) {
    int d = nd*16 + lr;
    int t0 = q0 + w*16 + lg*4;
    bf16* yp = yatt + ((size_t)(b*Tz + t0))*Cz + h*Dz + d;
    yp[0*Cz]   = (bf16)(o[nd][0] * i0);
    yp[1*Cz]   = (bf16)(o[nd][1] * i1);
    yp[2*Cz]   = (bf16)(o[nd][2] * i2);
    yp[3*Cz]   = (bf16)(o[nd][3] * i3);
  }
}

// ---------------- launch ----------------
extern "C" void kernel_launch(void* const* d_in, const int* in_sizes, int n_in,
                              void* d_out, int out_size, void* d_ws, size_t ws_size,
                              hipStream_t stream) {
  const float* x      = (const float*)d_in[0];
  const float* w_attn = (const float*)d_in[1];
  const float* b_attn = (const float*)d_in[2];
  const float* w_proj = (const float*)d_in[3];
  const float* b_proj = (const float*)d_in[4];

  float* y    = (float*)d_out;
  float* kout = y + YSZ;
  float* vout = y + 2*YSZ;

  char* ws = (char*)d_ws;
  bf16* xb   = (bf16*)ws;                     // 25165824 B (reused as yatt)
  bf16* qws  = (bf16*)(ws + 25165824);        // 25165824 B
  bf16* kb   = (bf16*)(ws + 50331648);        // 25165824 B
  bf16* vtb  = (bf16*)(ws + 75497472);        // 25165824 B
  bf16* wtA  = (bf16*)(ws + 100663296);       // 3538944 B
  bf16* wtP  = (bf16*)(ws + 104202240);       // 1179648 B
  bf16* yatt = xb;

  prep_x<<<2048, 256, 0, stream>>>(x, xb);
  transpose_conv<<<dim3(N3/32, Cz/32), 256, 0, stream>>>(w_attn, wtA, Cz, N3);
  transpose_conv<<<dim3(Cz/32, Cz/32), 256, 0, stream>>>(w_proj, wtP, Cz, Cz);

  gemm128<0><<<dim3((Mz/128)*(N3/128)), 256, 0, stream>>>(
      xb, wtA, Cz, Mz/128, N3/128, b_attn, qws, kb, vtb, kout, vout, nullptr);

  attn128<<<dim3((Tz/QBLK)*(Bz*Hz)), 512, 0, stream>>>(qws, kb, vtb, yatt);

  gemm128<1><<<dim3((Mz/128)*(Cz/128)), 256, 0, stream>>>(
      yatt, wtP, Cz, Mz/128, Cz/128, b_proj, nullptr, nullptr, nullptr,
      nullptr, nullptr, y);
}